// Round 2
// baseline (2783.277 us; speedup 1.0000x reference)
//
#include <hip/hip_runtime.h>
#include <stdint.h>
#include <stddef.h>

#define BB 4
#define LL 2048
#define DD 1024
#define HH 16
#define DKK 64
#define DFFN 4096

typedef __bf16 bf16;
typedef __attribute__((ext_vector_type(4))) float f32x4;
typedef __attribute__((ext_vector_type(8))) bf16 bf16x8;
typedef __attribute__((ext_vector_type(4))) bf16 bf16x4;

// ---------------------------------------------------------------- async copy
__device__ __forceinline__ void async_ld16(const void* g, void* l) {
  __builtin_amdgcn_global_load_lds(
      (const __attribute__((address_space(1))) void*)g,
      (__attribute__((address_space(3))) void*)l, 16, 0, 0);
}

// ---------------------------------------------------------------- fp32->bf16
__global__ __launch_bounds__(256) void cvt_kernel(
    const float* __restrict__ in, bf16* __restrict__ out, int n4) {
  int i = blockIdx.x * 256 + threadIdx.x;
  if (i >= n4) return;
  f32x4 v = ((const f32x4*)in)[i];
  bf16x4 o;
  o[0] = (bf16)v.x; o[1] = (bf16)v.y; o[2] = (bf16)v.z; o[3] = (bf16)v.w;
  ((bf16x4*)out)[i] = o;
}

// ---------------------------------------------------------------- layernorm
__global__ __launch_bounds__(256) void ln_kernel(
    const float* __restrict__ x, const float* __restrict__ gam,
    const float* __restrict__ bet, bf16* __restrict__ out) {
  int row = blockIdx.x;
  const float* xr = x + (size_t)row * DD;
  int t = threadIdx.x, wave = t >> 6, lane = t & 63;
  f32x4 v = *(const f32x4*)(xr + (t << 2));
  float s = v.x + v.y + v.z + v.w;
  float q2 = v.x * v.x + v.y * v.y + v.z * v.z + v.w * v.w;
#pragma unroll
  for (int off = 32; off; off >>= 1) {
    s += __shfl_xor(s, off);
    q2 += __shfl_xor(q2, off);
  }
  __shared__ float a1[4], a2[4];
  if (lane == 0) { a1[wave] = s; a2[wave] = q2; }
  __syncthreads();
  s = a1[0] + a1[1] + a1[2] + a1[3];
  q2 = a2[0] + a2[1] + a2[2] + a2[3];
  float mean = s * (1.0f / DD);
  float var = q2 * (1.0f / DD) - mean * mean;
  float rs = rsqrtf(var + 1e-6f);
  f32x4 g = *(const f32x4*)(gam + (t << 2));
  f32x4 b = *(const f32x4*)(bet + (t << 2));
  bf16x4 o;
  o[0] = (bf16)((v.x - mean) * rs * g.x + b.x);
  o[1] = (bf16)((v.y - mean) * rs * g.y + b.y);
  o[2] = (bf16)((v.z - mean) * rs * g.z + b.z);
  o[3] = (bf16)((v.w - mean) * rs * g.w + b.w);
  *(bf16x4*)&out[(size_t)row * DD + (t << 2)] = o;
}

// ---------------------------------------------------------------- BT GEMM
// C[M,N] = A[M,K] * B[N,K]^T.  BM=128 fixed, BK=32, 4 waves (2x2).
template <int BN, bool AF32, bool OUTF32, bool HASBIAS, bool DORELU,
          bool HASRES>
__global__ __launch_bounds__(256, 2) void gemm_bt(
    const void* __restrict__ Ain, const bf16* __restrict__ Bm,
    void* __restrict__ Cout, const float* __restrict__ bias,
    const float* __restrict__ res, int K, int ldc) {
  constexpr int BM = 128, BK = 32;
  constexpr int WN = BN / 32;  // j-tiles per wave
  static_assert(BN == 64 || BN == 128, "BN");
  __shared__ bf16 As[BM * BK];
  __shared__ bf16 Bs[BN * BK];
  int tid = threadIdx.x;
  int wave = tid >> 6, lane = tid & 63;
  int quad = lane >> 4, lm = lane & 15;
  int wm = wave & 1, wn = wave >> 1;
  int m0 = blockIdx.x * BM;
  int n0 = blockIdx.y * BN;

  const bf16* Ab = (const bf16*)Ain;
  const float* Af = (const float*)Ain;

  f32x4 acc[4][WN];
#pragma unroll
  for (int i = 0; i < 4; i++)
#pragma unroll
    for (int j = 0; j < WN; j++) acc[i][j] = (f32x4)0.0f;

  for (int k0 = 0; k0 < K; k0 += BK) {
    __syncthreads();
    // ---- stage A tile (128 x 32)
    if constexpr (AF32) {
#pragma unroll
      for (int it = 0; it < 2; ++it) {
        int chunk = tid + it * 256;  // 0..511, 8 elems each
        int row = chunk >> 2;
        int kc = (chunk & 3) << 3;
        const float* sp = Af + (size_t)(m0 + row) * K + k0 + kc;
        f32x4 u0 = *(const f32x4*)sp;
        f32x4 u1 = *(const f32x4*)(sp + 4);
        bf16x8 wv;
        wv[0] = (bf16)u0.x; wv[1] = (bf16)u0.y; wv[2] = (bf16)u0.z; wv[3] = (bf16)u0.w;
        wv[4] = (bf16)u1.x; wv[5] = (bf16)u1.y; wv[6] = (bf16)u1.z; wv[7] = (bf16)u1.w;
        *(bf16x8*)&As[chunk << 3] = wv;
      }
    } else {
#pragma unroll
      for (int it = 0; it < 2; ++it) {
        int chunk = it * 256 + (wave << 6) + lane;
        int row = chunk >> 2;
        int kc = (chunk & 3) << 3;
        async_ld16(Ab + (size_t)(m0 + row) * K + k0 + kc, &As[chunk << 3]);
      }
    }
    // ---- stage B tile (BN x 32)
#pragma unroll
    for (int it = 0; it < BN / 64; ++it) {
      int chunk = it * 256 + (wave << 6) + lane;
      int row = chunk >> 2;
      int kc = (chunk & 3) << 3;
      async_ld16(Bm + (size_t)(n0 + row) * K + k0 + kc, &Bs[chunk << 3]);
    }
    __syncthreads();
    // ---- fragments + MFMA
    bf16x8 af[4], bfr[WN];
#pragma unroll
    for (int i = 0; i < 4; i++)
      af[i] = *(const bf16x8*)&As[(((wm << 6) + (i << 4) + lm) << 5) + (quad << 3)];
#pragma unroll
    for (int j = 0; j < WN; j++)
      bfr[j] = *(const bf16x8*)&Bs[((wn * (BN / 2) + (j << 4) + lm) << 5) + (quad << 3)];
#pragma unroll
    for (int i = 0; i < 4; i++)
#pragma unroll
      for (int j = 0; j < WN; j++)
        acc[i][j] = __builtin_amdgcn_mfma_f32_16x16x32_bf16(af[i], bfr[j], acc[i][j], 0, 0, 0);
  }

  // ---- epilogue
  float* Cf = (float*)Cout;
  bf16* Cb = (bf16*)Cout;
#pragma unroll
  for (int i = 0; i < 4; i++) {
    int rowb = m0 + (wm << 6) + (i << 4) + (quad << 2);
#pragma unroll
    for (int r = 0; r < 4; r++) {
      int row = rowb + r;
#pragma unroll
      for (int j = 0; j < WN; j++) {
        int col = n0 + wn * (BN / 2) + (j << 4) + lm;
        float v = acc[i][j][r];
        if constexpr (HASBIAS) v += bias[col];
        if constexpr (DORELU) v = fmaxf(v, 0.0f);
        if constexpr (HASRES) v += res[(size_t)row * ldc + col];
        size_t cidx = (size_t)row * ldc + col;
        if constexpr (OUTF32) Cf[cidx] = v;
        else Cb[cidx] = (bf16)v;
      }
    }
  }
}

// ---------------------------------------------------------------- v -> vT
__global__ __launch_bounds__(256) void transpose_v(
    const bf16* __restrict__ qkv, bf16* __restrict__ vt) {
  __shared__ bf16 tile[64][65];
  int bh = blockIdx.y;
  int b = bh >> 4, h = bh & 15;
  int l0 = blockIdx.x << 6;
  int t = threadIdx.x;
  int d = t & 63, r = t >> 6;  // r in 0..3
#pragma unroll
  for (int i = 0; i < 16; i++) {
    int l = (i << 2) + r;
    tile[l][d] = qkv[((size_t)(b * LL) + l0 + l) * 3072 + 2048 + (h << 6) + d];
  }
  __syncthreads();
#pragma unroll
  for (int i = 0; i < 16; i++) {
    int dd = (i << 2) + r;
    vt[((size_t)bh * DKK + dd) * LL + l0 + d] = tile[d][dd];
  }
}

// ---------------------------------------------------------------- fused attn
// Per block: q-tile of 128 rows for one (b,h).  4 waves, each owns 32 rows.
// Pass 1: S = (q.k)*0.125*prior (masked), accumulate per-row sum(exp(S))
//         WITHOUT materializing S (no max subtraction: |S| <~ 8, exp-safe).
// Pass 2: recompute S, P = exp(S)/l, write fp32 attn output once, round-trip
//         P(bf16) through per-wave XOR-swizzled LDS, accumulate O = P.V.
// No __syncthreads anywhere: each wave only touches its own 32 LDS rows.
__global__ __launch_bounds__(256, 2) void fused_attn(
    const bf16* __restrict__ qkv, const bf16* __restrict__ vt,
    const float* __restrict__ prior, const int* __restrict__ mask,
    float* __restrict__ attn, bf16* __restrict__ o_flat) {
  __shared__ bf16 Pl[128 * 64];  // 16 KB, [row][key] with XOR swizzle
  const float SC = 0.125f * 1.44269504088896340736f;  // 1/temp * log2(e)
  int bh = blockIdx.y;
  int b = bh >> 4, h = bh & 15;
  int m0 = blockIdx.x << 7;
  int tid = threadIdx.x;
  int wave = tid >> 6, lane = tid & 63;
  int quad = lane >> 4, lm = lane & 15;
  int wrow = m0 + (wave << 5);  // this wave's first q row (within [0,2048))

  const bf16* qb = qkv + (size_t)(b * LL) * 3072 + (h << 6);
  const bf16* kb = qb + 1024;
  const float* pr = prior + (size_t)b * LL * LL;
  const int* mk = mask + b * LL;
  float* A = attn + (size_t)bh * LL * LL;
  const bf16* vb = vt + (size_t)bh * DKK * LL;

  // Q fragments (persist across both passes)
  bf16x8 aq[2][2];
#pragma unroll
  for (int i = 0; i < 2; i++)
#pragma unroll
    for (int ks = 0; ks < 2; ks++)
      aq[i][ks] = *(const bf16x8*)&qb[(size_t)(wrow + (i << 4) + lm) * 3072 +
                                      (ks << 5) + (quad << 3)];

  // ---------------- pass 1: row sums of exp(S)
  float lp[2][4];
#pragma unroll
  for (int i = 0; i < 2; i++)
#pragma unroll
    for (int r = 0; r < 4; r++) lp[i][r] = 0.0f;

  for (int kt = 0; kt < LL; kt += 64) {
    bf16x8 bk[4][2];
#pragma unroll
    for (int j = 0; j < 4; j++)
#pragma unroll
      for (int ks = 0; ks < 2; ks++)
        bk[j][ks] = *(const bf16x8*)&kb[(size_t)(kt + (j << 4) + lm) * 3072 +
                                        (ks << 5) + (quad << 3)];
    f32x4 s[2][4];
#pragma unroll
    for (int i = 0; i < 2; i++)
#pragma unroll
      for (int j = 0; j < 4; j++) {
        s[i][j] = __builtin_amdgcn_mfma_f32_16x16x32_bf16(aq[i][0], bk[j][0], (f32x4)0.0f, 0, 0, 0);
        s[i][j] = __builtin_amdgcn_mfma_f32_16x16x32_bf16(aq[i][1], bk[j][1], s[i][j], 0, 0, 0);
      }
    int msk[4];
#pragma unroll
    for (int j = 0; j < 4; j++) msk[j] = mk[kt + (j << 4) + lm];
#pragma unroll
    for (int i = 0; i < 2; i++)
#pragma unroll
      for (int r = 0; r < 4; r++) {
        int row = wrow + (i << 4) + (quad << 2) + r;
        const float* prow = pr + (size_t)row * LL + kt;
#pragma unroll
        for (int j = 0; j < 4; j++) {
          float pm = prow[(j << 4) + lm] * SC;
          float e = (msk[j] != 0) ? exp2f(s[i][j][r] * pm) : 0.0f;
          lp[i][r] += e;
        }
      }
  }
  // reduce partial sums across the 16 column-owner lanes (lm bits only)
#pragma unroll
  for (int i = 0; i < 2; i++)
#pragma unroll
    for (int r = 0; r < 4; r++) {
#pragma unroll
      for (int off = 1; off < 16; off <<= 1)
        lp[i][r] += __shfl_xor(lp[i][r], off);
      lp[i][r] = 1.0f / lp[i][r];  // reciprocal of row sum
    }

  // ---------------- pass 2: P out + O = P.V
  f32x4 of[2][4];
#pragma unroll
  for (int i = 0; i < 2; i++)
#pragma unroll
    for (int n = 0; n < 4; n++) of[i][n] = (f32x4)0.0f;

  for (int kt = 0; kt < LL; kt += 64) {
    bf16x8 bk[4][2];
#pragma unroll
    for (int j = 0; j < 4; j++)
#pragma unroll
      for (int ks = 0; ks < 2; ks++)
        bk[j][ks] = *(const bf16x8*)&kb[(size_t)(kt + (j << 4) + lm) * 3072 +
                                        (ks << 5) + (quad << 3)];
    f32x4 s[2][4];
#pragma unroll
    for (int i = 0; i < 2; i++)
#pragma unroll
      for (int j = 0; j < 4; j++) {
        s[i][j] = __builtin_amdgcn_mfma_f32_16x16x32_bf16(aq[i][0], bk[j][0], (f32x4)0.0f, 0, 0, 0);
        s[i][j] = __builtin_amdgcn_mfma_f32_16x16x32_bf16(aq[i][1], bk[j][1], s[i][j], 0, 0, 0);
      }
    int msk[4];
#pragma unroll
    for (int j = 0; j < 4; j++) msk[j] = mk[kt + (j << 4) + lm];
#pragma unroll
    for (int i = 0; i < 2; i++)
#pragma unroll
      for (int r = 0; r < 4; r++) {
        int row = wrow + (i << 4) + (quad << 2) + r;
        int rowl = (wave << 5) + (i << 4) + (quad << 2) + r;  // LDS row
        const float* prow = pr + (size_t)row * LL + kt;
        float* arow = A + (size_t)row * LL + kt;
#pragma unroll
        for (int j = 0; j < 4; j++) {
          int col = (j << 4) + lm;
          float pm = prow[col] * SC;
          float e = (msk[j] != 0) ? exp2f(s[i][j][r] * pm) * lp[i][r] : 0.0f;
          arow[col] = e;  // normalized attn prob, fp32 output
          Pl[(rowl << 6) + (col ^ ((rowl & 7) << 3))] = (bf16)e;
        }
      }
    // PV: O[32x64] += P[32x64] @ V[64x64]   (per wave, own LDS rows only)
    bf16x8 ap[2][2];
#pragma unroll
    for (int i = 0; i < 2; i++)
#pragma unroll
      for (int ks = 0; ks < 2; ks++) {
        int rowl = (wave << 5) + (i << 4) + lm;
        int elem = (rowl << 6) + ((((ks << 5) + (quad << 3))) ^ ((rowl & 7) << 3));
        ap[i][ks] = *(const bf16x8*)&Pl[elem];
      }
    bf16x8 bv[4][2];
#pragma unroll
    for (int n = 0; n < 4; n++)
#pragma unroll
      for (int ks = 0; ks < 2; ks++)
        bv[n][ks] = *(const bf16x8*)&vb[(size_t)((n << 4) + lm) * LL + kt +
                                        (ks << 5) + (quad << 3)];
#pragma unroll
    for (int i = 0; i < 2; i++)
#pragma unroll
      for (int n = 0; n < 4; n++) {
        of[i][n] = __builtin_amdgcn_mfma_f32_16x16x32_bf16(ap[i][0], bv[n][0], of[i][n], 0, 0, 0);
        of[i][n] = __builtin_amdgcn_mfma_f32_16x16x32_bf16(ap[i][1], bv[n][1], of[i][n], 0, 0, 0);
      }
  }

  // ---------------- epilogue: O -> o_flat [B*L, H*DV] bf16
#pragma unroll
  for (int i = 0; i < 2; i++)
#pragma unroll
    for (int r = 0; r < 4; r++) {
      int row = wrow + (i << 4) + (quad << 2) + r;
      bf16* orow = o_flat + (size_t)(b * LL + row) * DD + (h << 6);
#pragma unroll
      for (int n = 0; n < 4; n++) orow[(n << 4) + lm] = (bf16)of[i][n][r];
    }
}

// ---------------------------------------------------------------- launch
extern "C" void kernel_launch(void* const* d_in, const int* in_sizes, int n_in,
                              void* d_out, int out_size, void* d_ws,
                              size_t ws_size, hipStream_t stream) {
  const float* src = (const float*)d_in[0];
  const int* mask = (const int*)d_in[1];
  const float* prior = (const float*)d_in[2];
  const float* ln1_g = (const float*)d_in[3];
  const float* ln1_b = (const float*)d_in[4];
  const float* wq = (const float*)d_in[5];
  const float* wk = (const float*)d_in[6];
  const float* wv = (const float*)d_in[7];
  const float* fc_w = (const float*)d_in[8];
  const float* ln2_g = (const float*)d_in[9];
  const float* ln2_b = (const float*)d_in[10];
  const float* w1_w = (const float*)d_in[11];
  const float* w1_b = (const float*)d_in[12];
  const float* w2_w = (const float*)d_in[13];
  const float* w2_b = (const float*)d_in[14];

  float* y_out = (float*)d_out;
  float* attn_out = y_out + (size_t)BB * LL * DD;

  // ---- workspace layout with liveness-based aliasing ----
  char* w = (char*)d_ws;
  bf16* wqkv_b = (bf16*)w;  w += (size_t)3072 * 1024 * 2;   //  6 MB persistent
  bf16* wfc_b = (bf16*)w;   w += (size_t)1024 * 1024 * 2;   //  2 MB persistent
  bf16* w1b16 = (bf16*)w;   w += (size_t)4096 * 1024 * 2;   //  8 MB persistent
  bf16* w2b16 = (bf16*)w;   w += (size_t)1024 * 4096 * 2;   //  8 MB persistent
  char* regB = w;           w += (size_t)8192 * 1024 * 2;   // 16 MB: x_b -> o_flat
  char* regC = w;           w += (size_t)8192 * 3072 * 2;   // 48 MB: qkv_flat -> z_b + h_b(head)
  char* regD = w;           w += (size_t)3 * 8388608 * 2;   // 48 MB: vt -> h_b(tail)
  float* y1 = (float*)w;    w += (size_t)8192 * 1024 * 4;   // 32 MB persistent (fc->end)

  bf16* x_b = (bf16*)regB;        // live: LN1 -> QKV gemm
  bf16* o_flat = (bf16*)regB;     // live: fused attn -> fc gemm (x_b dead)
  bf16* qkv_flat = (bf16*)regC;   // live: QKV gemm -> fused attn
  bf16* z_b = (bf16*)regC;        // live: LN2 -> FFN1 (qkv dead)
  bf16* h_b = (bf16*)(regC + (size_t)8192 * 1024 * 2);  // 64 MB spanning C-tail + D-head
                                   // live: FFN1 -> FFN2 (qkv, vt-unused-half dead)
  bf16* vt = (bf16*)(regD + (size_t)2 * 8388608 * 2);   // clear of h_b span

  // weights -> bf16
  cvt_kernel<<<1024, 256, 0, stream>>>(wq, wqkv_b, 262144);
  cvt_kernel<<<1024, 256, 0, stream>>>(wk, wqkv_b + 1024 * 1024, 262144);
  cvt_kernel<<<1024, 256, 0, stream>>>(wv, wqkv_b + 2 * 1024 * 1024, 262144);
  cvt_kernel<<<1024, 256, 0, stream>>>(fc_w, wfc_b, 262144);
  cvt_kernel<<<4096, 256, 0, stream>>>(w1_w, w1b16, 1048576);
  cvt_kernel<<<4096, 256, 0, stream>>>(w2_w, w2b16, 1048576);

  // LN1
  ln_kernel<<<8192, 256, 0, stream>>>(src, ln1_g, ln1_b, x_b);
  // QKV projection: [8192,1024] x [3072,1024]^T -> [8192,3072] bf16
  gemm_bt<128, false, false, false, false, false>
      <<<dim3(64, 24, 1), 256, 0, stream>>>(x_b, wqkv_b, qkv_flat, nullptr, nullptr, 1024, 3072);
  // v -> vT per head (for PV B-operand)
  transpose_v<<<dim3(32, 64, 1), 256, 0, stream>>>(qkv_flat, vt);
  // fused: scores (+prior,+mask) + softmax + attn write + O = P@V
  fused_attn<<<dim3(16, 64, 1), 256, 0, stream>>>(qkv_flat, vt, prior, mask,
                                                  attn_out, o_flat);
  // y1 = O @ fc_w^T + src
  gemm_bt<128, false, true, false, false, true>
      <<<dim3(64, 8, 1), 256, 0, stream>>>(o_flat, wfc_b, y1, nullptr, src, 1024, 1024);
  // LN2
  ln_kernel<<<8192, 256, 0, stream>>>(y1, ln2_g, ln2_b, z_b);
  // h = relu(z @ w1^T + b1)
  gemm_bt<128, false, false, true, true, false>
      <<<dim3(64, 32, 1), 256, 0, stream>>>(z_b, w1b16, h_b, w1_b, nullptr, 1024, 4096);
  // y = h @ w2^T + b2 + y1  -> d_out
  gemm_bt<128, false, true, true, false, true>
      <<<dim3(64, 8, 1), 256, 0, stream>>>(h_b, w2b16, y_out, w2_b, y1, 4096, 1024);
}